// Round 7
// baseline (680.310 us; speedup 1.0000x reference)
//
#include <hip/hip_runtime.h>

typedef unsigned short u16;
typedef __attribute__((ext_vector_type(8))) short bf16x8;
typedef __attribute__((ext_vector_type(4))) float f32x4;

__device__ inline float bf2f(u16 h) {
    union { unsigned u; float f; } v; v.u = ((unsigned)h) << 16; return v.f;
}
__device__ inline u16 f2bf(float f) {
    union { float f; unsigned u; } v; v.f = f;
    unsigned r = v.u + 0x7fffu + ((v.u >> 16) & 1u);
    return (u16)(r >> 16);
}

__device__ inline void gl_lds16(const u16* g, u16* l) {
    __builtin_amdgcn_global_load_lds(
        (const __attribute__((address_space(1))) void*)g,
        (__attribute__((address_space(3))) void*)l, 16, 0, 0);
}

// ---------------------------------------------------------------------------
// GEMM: C[M,N] = (A[M,K] @ Bt[N,K]^T) * scale + bias[N]
// AF32/BF32: operand f32 in global (float4 load + convert to bf16 in LDS);
// else bf16 (async global_load_lds 16B). COUTF32: C written as f32, else bf16.
// 128x128 tile, BK=32, 256 thr (4 waves 2x2 of 64x64), 16x16x32 bf16 MFMA.
// ---------------------------------------------------------------------------
#define BM 128
#define BN 128
#define BK 32

template <int AF32, int BF32, int COUTF32>
__global__ __launch_bounds__(256, 2) void gemm_bt(
    const void* __restrict__ Av, const void* __restrict__ Bv,
    const float* __restrict__ bias, void* __restrict__ Cv,
    int M, int N, int K, float scale,
    long long sAb, long long sBb, long long sCb)
{
    __shared__ u16 As[BM * BK];
    __shared__ u16 Bs[BN * BK];

    int b = blockIdx.z;
    int bm0 = blockIdx.x * BM;
    int bn0 = blockIdx.y * BN;
    int tid = threadIdx.x;
    int w = tid >> 6, l = tid & 63;
    int wm = (w >> 1) * 64, wn = (w & 1) * 64;
    int lane15 = l & 15, quad = l >> 4;
    int lr = l >> 2;            // row within 16-row staging chunk
    int lc = (l & 3) * 8;       // elem offset within 32-elem row

    f32x4 acc[4][4];
#pragma unroll
    for (int i = 0; i < 4; i++)
#pragma unroll
        for (int j = 0; j < 4; j++) acc[i][j] = (f32x4)(0.0f);

    const u16*   Ag16 = (const u16*)Av   + (long long)b * sAb
                        + (long long)(bm0 + w * 32 + lr) * K + lc;
    const float* Ag32 = (const float*)Av + (long long)b * sAb
                        + (long long)(bm0 + w * 32 + lr) * K + lc;
    const u16*   Bg16 = (const u16*)Bv   + (long long)b * sBb
                        + (long long)(bn0 + w * 32 + lr) * K + lc;
    const float* Bg32 = (const float*)Bv + (long long)b * sBb
                        + (long long)(bn0 + w * 32 + lr) * K + lc;

    for (int k0 = 0; k0 < K; k0 += BK) {
        if (AF32) {
#pragma unroll
            for (int c = 0; c < 2; c++) {
                const float* src = Ag32 + (long long)c * 16 * K + k0;
                float4 a0 = *(const float4*)(src);
                float4 a1 = *(const float4*)(src + 4);
                u16 tmp[8];
                tmp[0] = f2bf(a0.x); tmp[1] = f2bf(a0.y);
                tmp[2] = f2bf(a0.z); tmp[3] = f2bf(a0.w);
                tmp[4] = f2bf(a1.x); tmp[5] = f2bf(a1.y);
                tmp[6] = f2bf(a1.z); tmp[7] = f2bf(a1.w);
                *(bf16x8*)&As[(w * 32 + c * 16) * BK + l * 8] = *(const bf16x8*)tmp;
            }
        } else {
            gl_lds16(Ag16 + k0,             &As[(w * 32) * BK]);
            gl_lds16(Ag16 + 16LL * K + k0,  &As[(w * 32 + 16) * BK]);
        }
        if (BF32) {
#pragma unroll
            for (int c = 0; c < 2; c++) {
                const float* src = Bg32 + (long long)c * 16 * K + k0;
                float4 a0 = *(const float4*)(src);
                float4 a1 = *(const float4*)(src + 4);
                u16 tmp[8];
                tmp[0] = f2bf(a0.x); tmp[1] = f2bf(a0.y);
                tmp[2] = f2bf(a0.z); tmp[3] = f2bf(a0.w);
                tmp[4] = f2bf(a1.x); tmp[5] = f2bf(a1.y);
                tmp[6] = f2bf(a1.z); tmp[7] = f2bf(a1.w);
                *(bf16x8*)&Bs[(w * 32 + c * 16) * BK + l * 8] = *(const bf16x8*)tmp;
            }
        } else {
            gl_lds16(Bg16 + k0,             &Bs[(w * 32) * BK]);
            gl_lds16(Bg16 + 16LL * K + k0,  &Bs[(w * 32 + 16) * BK]);
        }
        __syncthreads();

        bf16x8 af[4], bfr[4];
#pragma unroll
        for (int i = 0; i < 4; i++) {
            af[i]  = *(const bf16x8*)&As[(wm + i * 16 + lane15) * BK + quad * 8];
            bfr[i] = *(const bf16x8*)&Bs[(wn + i * 16 + lane15) * BK + quad * 8];
        }
#pragma unroll
        for (int i = 0; i < 4; i++)
#pragma unroll
            for (int j = 0; j < 4; j++)
                acc[i][j] = __builtin_amdgcn_mfma_f32_16x16x32_bf16(
                    af[i], bfr[j], acc[i][j], 0, 0, 0);
        __syncthreads();
    }

    // C/D layout: col = lane&15, row = quad*4 + reg
    u16*   C16 = (u16*)Cv   + (long long)b * sCb;
    float* C32 = (float*)Cv + (long long)b * sCb;
#pragma unroll
    for (int j = 0; j < 4; j++) {
        int col = bn0 + wn + j * 16 + lane15;
        float bv = bias ? bias[col] : 0.0f;
#pragma unroll
        for (int i = 0; i < 4; i++) {
            int row0 = bm0 + wm + i * 16 + quad * 4;
#pragma unroll
            for (int r = 0; r < 4; r++) {
                float v = acc[i][j][r] * scale + bv;
                if (COUTF32) C32[(long long)(row0 + r) * N + col] = v;
                else         C16[(long long)(row0 + r) * N + col] = f2bf(v);
            }
        }
    }
}

// ---------------------------------------------------------------------------
__global__ __launch_bounds__(256) void transpose_k(const u16* __restrict__ V,
                                                   u16* __restrict__ Vt)
{
    __shared__ u16 tile[64][65];
    int b = blockIdx.z;
    int s0 = blockIdx.x * 64, d0 = blockIdx.y * 64;
    const u16* Vb = V + (long long)b * 2048 * 1024;
    u16* Vtb = Vt + (long long)b * 1024 * 2048;
    int tx = threadIdx.x & 63, ty = threadIdx.x >> 6;
#pragma unroll
    for (int i = ty; i < 64; i += 4)
        tile[i][tx] = Vb[(long long)(s0 + i) * 1024 + d0 + tx];
    __syncthreads();
#pragma unroll
    for (int i = ty; i < 64; i += 4)
        Vtb[(long long)(d0 + i) * 2048 + s0 + tx] = tile[tx][i];
}

// ---------------------------------------------------------------------------
// Row softmax in-place: 8192 rows of 2048 bf16
// ---------------------------------------------------------------------------
__global__ __launch_bounds__(256) void softmax_k(u16* __restrict__ Sc)
{
    long long row = blockIdx.x;
    u16* s = Sc + row * 2048;
    int t = threadIdx.x;

    uint4 raw = *(const uint4*)(s + t * 8);
    const u16* rp = (const u16*)&raw;
    float v[8];
    float mx = -3.4e38f;
#pragma unroll
    for (int j = 0; j < 8; j++) { v[j] = bf2f(rp[j]); mx = fmaxf(mx, v[j]); }
#pragma unroll
    for (int o = 32; o > 0; o >>= 1) mx = fmaxf(mx, __shfl_xor(mx, o));
    __shared__ float redm[4];
    if ((t & 63) == 0) redm[t >> 6] = mx;
    __syncthreads();
    mx = fmaxf(fmaxf(redm[0], redm[1]), fmaxf(redm[2], redm[3]));

    float sum = 0.0f;
#pragma unroll
    for (int j = 0; j < 8; j++) { v[j] = __expf(v[j] - mx); sum += v[j]; }
#pragma unroll
    for (int o = 32; o > 0; o >>= 1) sum += __shfl_xor(sum, o);
    __shared__ float reds[4];
    if ((t & 63) == 0) reds[t >> 6] = sum;
    __syncthreads();
    sum = reds[0] + reds[1] + reds[2] + reds[3];

    float inv = 1.0f / sum;
    u16 o8[8];
#pragma unroll
    for (int j = 0; j < 8; j++) o8[j] = f2bf(v[j] * inv);
    *(uint4*)(s + t * 8) = *(const uint4*)o8;
}

// ---------------------------------------------------------------------------
__global__ __launch_bounds__(256) void gate_partial(const u16* __restrict__ h,
                                                    const float* __restrict__ Wg,
                                                    float* __restrict__ part)
{
    int b = blockIdx.x, c = blockIdx.y;
    const u16* hb = h + (long long)b * 2048 * 1024 + (long long)c * 64 * 1024;
    int t = threadIdx.x;
    float acc = 0.0f;
    for (int s = 0; s < 64; s++) {
        for (int d = t; d < 1024; d += 256)
            acc += bf2f(hb[s * 1024 + d]) * Wg[d];
    }
#pragma unroll
    for (int o = 32; o > 0; o >>= 1) acc += __shfl_xor(acc, o);
    __shared__ float red[4];
    if ((t & 63) == 0) red[t >> 6] = acc;
    __syncthreads();
    if (t == 0) part[b * 32 + c] = red[0] + red[1] + red[2] + red[3];
}

__global__ void gate_final(const float* __restrict__ part,
                           const float* __restrict__ bg, float* __restrict__ outp)
{
    int t = threadIdx.x;
    if (t < 4) {
        float s = 0.0f;
        for (int c = 0; c < 32; c++) s += part[t * 32 + c];
        float v = s * (1.0f / 2048.0f) + bg[0];
        outp[t] = 1.0f / (1.0f + __expf(-v));
    }
}

// ---------------------------------------------------------------------------
// Epilogue: z = relu(mu + eps*exp(0.5*logvar)); out = LN(x+z)*gamma+beta
// All f32.
// ---------------------------------------------------------------------------
__global__ __launch_bounds__(256) void epilogue_k(
    const float* __restrict__ x, const float* __restrict__ ep,
    const float* __restrict__ mu, const float* __restrict__ lv,
    const float* __restrict__ gamma, const float* __restrict__ beta,
    float* __restrict__ out)
{
    long long base = (long long)blockIdx.x * 1024;
    int t = threadIdx.x;
    float y[4];
    float sum = 0.0f, sq = 0.0f;
#pragma unroll
    for (int j = 0; j < 4; j++) {
        int i = j * 256 + t;
        float xv = x[base + i];
        float ev = ep[base + i];
        float m  = mu[base + i];
        float sd = __expf(0.5f * lv[base + i]);
        float z  = fmaxf(m + ev * sd, 0.0f);
        float yy = xv + z;
        y[j] = yy; sum += yy; sq += yy * yy;
    }
#pragma unroll
    for (int o = 32; o > 0; o >>= 1) { sum += __shfl_xor(sum, o); sq += __shfl_xor(sq, o); }
    __shared__ float rs[4], rq[4];
    if ((t & 63) == 0) { rs[t >> 6] = sum; rq[t >> 6] = sq; }
    __syncthreads();
    sum = rs[0] + rs[1] + rs[2] + rs[3];
    sq  = rq[0] + rq[1] + rq[2] + rq[3];
    float mean = sum * (1.0f / 1024.0f);
    float var  = fmaxf(sq * (1.0f / 1024.0f) - mean * mean, 0.0f);
    float rstd = rsqrtf(var + 1e-5f);
#pragma unroll
    for (int j = 0; j < 4; j++) {
        int i = j * 256 + t;
        out[base + i] = (y[j] - mean) * rstd * gamma[i] + beta[i];
    }
}

// ---------------------------------------------------------------------------
extern "C" void kernel_launch(void* const* d_in, const int* in_sizes, int n_in,
                              void* d_out, int out_size, void* d_ws, size_t ws_size,
                              hipStream_t stream)
{
    // Inputs: float32. Outputs: float32 (out, mu, logvar, p_gate concat).
    const float* x     = (const float*)d_in[0];
    const float* ep    = (const float*)d_in[1];
    const float* Wq    = (const float*)d_in[2];
    const float* bq    = (const float*)d_in[3];
    const float* Wk    = (const float*)d_in[4];
    const float* bk    = (const float*)d_in[5];
    const float* Wv    = (const float*)d_in[6];
    const float* bv    = (const float*)d_in[7];
    const float* Wmu   = (const float*)d_in[8];
    const float* bmu   = (const float*)d_in[9];
    const float* Wlv   = (const float*)d_in[10];
    const float* blv   = (const float*)d_in[11];
    const float* Wg    = (const float*)d_in[12];
    const float* bg    = (const float*)d_in[13];
    const float* gamma = (const float*)d_in[14];
    const float* beta  = (const float*)d_in[15];
    float* out = (float*)d_out;

    const int M = 8192;       // B*S
    const int D = 1024;
    const int S = 2048;

    // f32 output regions (elements):
    float* mu_out = out + 8388608LL;   // bytes [33.55MB, 67.11MB)
    float* lv_out = out + 16777216LL;  // bytes [67.11MB, 100.66MB)
    float* pg_out = out + 25165824LL;  // 4 floats

    // bf16 scratch overlays inside d_out (each region is 33.55MB):
    //   out region: Sc/P (33.55MB bf16)  — dead until step 11
    //   mu region:  Q | K (16.78MB each) — dead until step 8
    //   lv region:  V | Vt               — dead until step 9
    // ws: h only (exactly 16,777,216 bytes).
    u16* Sc = (u16*)out;
    u16* Q  = (u16*)mu_out;
    u16* Kb = (u16*)mu_out + 8388608LL;
    u16* V  = (u16*)lv_out;
    u16* Vt = (u16*)lv_out + 8388608LL;
    u16* h  = (u16*)d_ws;
    float* part = (float*)out;   // 512B in dead Sc region (steps 8-10)

    dim3 blk(256);

    // 1-2. Q = x@Wq^T+bq, K = x@Wk^T+bk   (f32 in, bf16 out)
    gemm_bt<1, 1, 0><<<dim3(64, 8, 1), blk, 0, stream>>>(x, Wq, bq, Q,  M, D, D, 1.0f, 0, 0, 0);
    gemm_bt<1, 1, 0><<<dim3(64, 8, 1), blk, 0, stream>>>(x, Wk, bk, Kb, M, D, D, 1.0f, 0, 0, 0);

    // 3. scores = Q @ K^T / 48 per batch -> Sc (bf16)
    gemm_bt<0, 0, 0><<<dim3(16, 16, 4), blk, 0, stream>>>(Q, Kb, nullptr, Sc, S, S, D,
        1.0f / 48.0f, (long long)S * D, (long long)S * D, (long long)S * S);

    // 4. softmax in place
    softmax_k<<<dim3(8192), blk, 0, stream>>>(Sc);

    // 5. V = x@Wv^T+bv -> lv region (bf16)
    gemm_bt<1, 1, 0><<<dim3(64, 8, 1), blk, 0, stream>>>(x, Wv, bv, V, M, D, D, 1.0f, 0, 0, 0);

    // 6. V^T per batch
    transpose_k<<<dim3(32, 16, 4), blk, 0, stream>>>(V, Vt);

    // 7. h = P @ V (via Vt) per batch -> ws (bf16); consumes Sc
    gemm_bt<0, 0, 0><<<dim3(16, 8, 4), blk, 0, stream>>>(Sc, Vt, nullptr, h, S, D, S,
        1.0f, (long long)S * S, (long long)D * S, (long long)S * D);

    // 8-9. mu, logvar -> f32 outputs (Q/K dead; V/Vt dead)
    gemm_bt<0, 1, 1><<<dim3(64, 8, 1), blk, 0, stream>>>(h, Wmu, bmu, mu_out, M, D, D, 1.0f, 0, 0, 0);
    gemm_bt<0, 1, 1><<<dim3(64, 8, 1), blk, 0, stream>>>(h, Wlv, blv, lv_out, M, D, D, 1.0f, 0, 0, 0);

    // 10. gate -> f32 p_gate
    gate_partial<<<dim3(4, 32), blk, 0, stream>>>(h, Wg, part);
    gate_final<<<dim3(1), dim3(64), 0, stream>>>(part, bg, pg_out);

    // 11. out = LN(x + relu(mu + eps*exp(0.5*logvar))) -> f32 (overwrites Sc/part)
    epilogue_k<<<dim3(8192), blk, 0, stream>>>(x, ep, mu_out, lv_out, gamma, beta, out);
}